// Round 1
// baseline (215.148 us; speedup 1.0000x reference)
//
#include <hip/hip_runtime.h>
#include <math.h>

#define N_ATOMS 512
#define MAX_B 128
#define WINDOW 14

__global__ void zero_hist_kernel(float* hist, int B) {
    int t = threadIdx.x;
    if (t < B) hist[t] = 0.0f;
}

__global__ __launch_bounds__(256) void pair_kernel(
    const float* __restrict__ traj, const float* __restrict__ cell,
    const float* __restrict__ r_list, float* __restrict__ hist,
    int B, int chunks)
{
    __shared__ float qx[N_ATOMS], qy[N_ATOMS], qz[N_ATOMS];
    __shared__ float sh[MAX_B];
    __shared__ float rl[MAX_B];

    const int frame = blockIdx.x / chunks;
    const int chunk = blockIdx.x % chunks;
    const int tid = threadIdx.x;
    const int nthreads = blockDim.x;

    // Stage this frame's coordinates into LDS (SoA).
    const float* q = traj + (size_t)frame * N_ATOMS * 3;
    for (int a = tid; a < N_ATOMS; a += nthreads) {
        qx[a] = q[3 * a + 0];
        qy[a] = q[3 * a + 1];
        qz[a] = q[3 * a + 2];
    }
    for (int k = tid; k < B; k += nthreads) {
        sh[k] = 0.0f;
        rl[k] = r_list[k];
    }
    __syncthreads();

    const float L = cell[0];
    const float invL = 1.0f / L;
    const float cutoff_sq = (L * 0.5f) * (L * 0.5f);
    const float r0 = rl[0];
    const float inv_dr = 10.0f;   // 1/DR, DR = 0.1

    const int P = N_ATOMS * (N_ATOMS - 1) / 2;  // pairs per frame
    const int per = (P + chunks - 1) / chunks;
    const int p_lo = chunk * per;
    const int p_hi = (p_lo + per < P) ? (p_lo + per) : P;

    // start(i) = i*(2N-1-i)/2 : first linear pair index of row i
    auto row_start = [](int i) { return i * (2 * N_ATOMS - 1 - i) / 2; };

    for (int p = p_lo + tid; p < p_hi; p += nthreads) {
        // Decode (i, j) from the linear upper-triangle index p.
        const double tn = 2.0 * N_ATOMS - 1.0;
        int i = (int)((tn - sqrt(tn * tn - 8.0 * (double)p)) * 0.5);
        if (i < 0) i = 0;
        while (i > 0 && row_start(i) > p) --i;
        while (row_start(i + 1) <= p) ++i;
        const int j = i + 1 + (p - row_start(i));

        // Minimum-image displacement (same arithmetic as reference).
        float dx = qx[j] - qx[i];
        float dy = qy[j] - qy[i];
        float dz = qz[j] - qz[i];
        dx -= L * floorf(dx * invL + 0.5f);
        dy -= L * floorf(dy * invL + 0.5f);
        dz -= L * floorf(dz * invL + 0.5f);
        const float d2 = dx * dx + dy * dy + dz * dz;

        if (d2 < cutoff_sq && d2 != 0.0f) {
            const float d = sqrtf(d2);
            int kc = (int)floorf((d - r0) * inv_dr + 0.5f);
            int klo = kc - WINDOW; if (klo < 0) klo = 0;
            int khi = kc + WINDOW; if (khi > B - 1) khi = B - 1;
            for (int k = klo; k <= khi; ++k) {
                const float t = (d - rl[k]) * inv_dr;
                const float w = __expf(-0.5f * t * t);
                atomicAdd(&sh[k], w);
            }
        }
    }
    __syncthreads();

    for (int k = tid; k < B; k += nthreads) {
        atomicAdd(&hist[k], sh[k]);
    }
}

__global__ void finalize_kernel(const float* __restrict__ r_list,
                                const float* __restrict__ cell,
                                const float* __restrict__ hist,
                                float* __restrict__ out, int B, int F) {
    const int k = blockIdx.x * blockDim.x + threadIdx.x;
    if (k >= B) return;
    const float r = r_list[k];
    out[k] = r;  // output 0: r_list (d_out is re-poisoned every call)

    const float det = cell[0] * cell[4] * cell[8];
    const float rp = r + 0.05f;
    const float rm = r - 0.05f;
    const float v = (4.0f * (float)M_PI / 3.0f) * (rp * rp * rp - rm * rm * rm);
    const float inv_sqrt2pi = 0.3989422804014327f;
    const float h = hist[k] * inv_sqrt2pi / (float)F;
    const float gr = h / v * det / (float)(N_ATOMS - 1) / (float)N_ATOMS * 2.0f;
    out[B + k] = gr;
}

extern "C" void kernel_launch(void* const* d_in, const int* in_sizes, int n_in,
                              void* d_out, int out_size, void* d_ws, size_t ws_size,
                              hipStream_t stream) {
    const float* traj   = (const float*)d_in[0];
    const float* cell   = (const float*)d_in[1];
    const float* r_list = (const float*)d_in[2];
    float* out  = (float*)d_out;
    float* hist = (float*)d_ws;

    const int B = in_sizes[2];
    const int F = in_sizes[0] / (N_ATOMS * 3);
    const int chunks = 64;

    hipLaunchKernelGGL(zero_hist_kernel, dim3(1), dim3(MAX_B), 0, stream, hist, B);
    hipLaunchKernelGGL(pair_kernel, dim3(F * chunks), dim3(256), 0, stream,
                       traj, cell, r_list, hist, B, chunks);
    hipLaunchKernelGGL(finalize_kernel, dim3(1), dim3(MAX_B), 0, stream,
                       r_list, cell, hist, out, B, F);
}

// Round 2
// 106.931 us; speedup vs baseline: 2.0120x; 2.0120x over previous
//
#include <hip/hip_runtime.h>
#include <math.h>

#define N_ATOMS 512
#define NPAIRS (N_ATOMS * (N_ATOMS - 1) / 2)   // 130816
#define MAX_B 128

__global__ void zero_hist_kernel(float* hist, int n) {
    for (int t = threadIdx.x; t < n; t += blockDim.x) hist[t] = 0.0f;
}

__global__ __launch_bounds__(256) void pair_kernel(
    const float* __restrict__ traj, const float* __restrict__ cell,
    const float* __restrict__ r_list, float* __restrict__ hist,
    int B, int chunks, int reps)
{
    __shared__ float qx[N_ATOMS], qy[N_ATOMS], qz[N_ATOMS];
    __shared__ float dbuf[2][256];   // compacted distances, double-buffered
    __shared__ int   nvbuf[2][4];    // valid count per wave segment
    __shared__ float accbuf[256];

    const int frame = blockIdx.x / chunks;
    const int chunk = blockIdx.x % chunks;
    const int tid   = threadIdx.x;
    const int lane  = tid & 63;
    const int wid   = tid >> 6;

    // Stage frame coords into LDS (SoA).
    const float* q = traj + (size_t)frame * (N_ATOMS * 3);
    for (int a = tid; a < N_ATOMS; a += 256) {
        qx[a] = q[3 * a + 0];
        qy[a] = q[3 * a + 1];
        qz[a] = q[3 * a + 2];
    }

    const float L = cell[0];
    const float invL = 1.0f / L;
    const float cutoff_sq = 0.25f * L * L;

    // Bin ownership: thread (g, k) accumulates bin k over distances j ≡ g (mod 2).
    const int g = tid >> 7;          // parity group 0/1
    const int k = tid & 127;
    const bool active = (k < B);
    const float rk = active ? r_list[k] : 0.0f;
    // w = exp(-50 (d - rk)^2) = exp(d*(c1*d + c2) + c3)
    const float c1 = -50.0f;
    const float c2 = 100.0f * rk;
    const float c3 = -50.0f * rk * rk;
    float acc = 0.0f;

    const int per  = (NPAIRS + chunks - 1) / chunks;
    const int p_lo = chunk * per;
    const int p_hi = (p_lo + per < NPAIRS) ? (p_lo + per) : NPAIRS;
    const int rounds = (per + 255) / 256;

    __syncthreads();   // coords ready

    for (int r = 0; r < rounds; ++r) {
        const int b = r & 1;

        // ---- phase 1: compute distance for pair p, compact per wave ----
        int p = p_lo + r * 256 + tid;
        float dval = 0.0f;
        bool valid = false;
        if (p < p_hi) {
            // decode upper-triangle (i, j) from linear index p
            const double tn = 2.0 * N_ATOMS - 1.0;   // 1023
            int i = (int)((tn - sqrt(tn * tn - 8.0 * (double)p)) * 0.5);
            if (i < 0) i = 0;
            auto row_start = [](int i_) { return i_ * (2 * N_ATOMS - 1 - i_) / 2; };
            while (i > 0 && row_start(i) > p) --i;
            while (row_start(i + 1) <= p) ++i;
            const int j = i + 1 + (p - row_start(i));

            float dx = qx[j] - qx[i];
            float dy = qy[j] - qy[i];
            float dz = qz[j] - qz[i];
            dx -= L * floorf(dx * invL + 0.5f);
            dy -= L * floorf(dy * invL + 0.5f);
            dz -= L * floorf(dz * invL + 0.5f);
            const float d2 = dx * dx + dy * dy + dz * dz;
            if (d2 < cutoff_sq && d2 != 0.0f) {
                valid = true;
                dval = sqrtf(d2);
            }
        }
        const unsigned long long mask = __ballot(valid);
        const int nv  = __popcll(mask);
        const int pos = __popcll(mask & ((1ull << lane) - 1ull));
        if (valid) dbuf[b][wid * 64 + pos] = dval;
        if (lane == 0) nvbuf[b][wid] = nv;

        __syncthreads();   // dbuf[b]/nvbuf[b] ready; also licenses round r+1's
                           // writes to buffer b^1 (prev reads of b^1 complete)

        // ---- phase 2: bin-centric accumulation over compacted distances ----
        if (active) {
            #pragma unroll
            for (int w = 0; w < 4; ++w) {
                const int cw = nvbuf[b][w];
                const float* db = &dbuf[b][w * 64];
                for (int j = g; j < cw; j += 2) {
                    const float d = db[j];                       // wave-broadcast read
                    const float arg = fmaf(d, fmaf(c1, d, c2), c3);
                    acc += __expf(arg);
                }
            }
        }
        // no trailing barrier: double-buffering + next round's barrier order it
    }

    accbuf[tid] = acc;
    __syncthreads();
    if (tid < B) {
        const int rep = (int)(blockIdx.x % (unsigned)reps);
        atomicAdd(&hist[rep * MAX_B + tid], accbuf[tid] + accbuf[tid + 128]);
    }
}

__global__ void finalize_kernel(const float* __restrict__ r_list,
                                const float* __restrict__ cell,
                                const float* __restrict__ hist,
                                float* __restrict__ out, int B, int F, int reps) {
    const int k = blockIdx.x * blockDim.x + threadIdx.x;
    if (k >= B) return;
    const float r = r_list[k];
    out[k] = r;   // output 0: r_list (d_out re-poisoned every call)

    float h = 0.0f;
    for (int rep = 0; rep < reps; ++rep) h += hist[rep * MAX_B + k];

    const float det = cell[0] * cell[4] * cell[8];
    const float rp = r + 0.05f;
    const float rm = r - 0.05f;
    const float v = (4.0f * (float)M_PI / 3.0f) * (rp * rp * rp - rm * rm * rm);
    const float inv_sqrt2pi = 0.3989422804014327f;
    h = h * inv_sqrt2pi / (float)F;
    const float gr = h / v * det / (float)(N_ATOMS - 1) / (float)N_ATOMS * 2.0f;
    out[MAX_B ? (B + k) : (B + k)] = gr;   // out[B + k]
}

extern "C" void kernel_launch(void* const* d_in, const int* in_sizes, int n_in,
                              void* d_out, int out_size, void* d_ws, size_t ws_size,
                              hipStream_t stream) {
    const float* traj   = (const float*)d_in[0];
    const float* cell   = (const float*)d_in[1];
    const float* r_list = (const float*)d_in[2];
    float* out  = (float*)d_out;
    float* hist = (float*)d_ws;

    const int B = in_sizes[2];
    const int F = in_sizes[0] / (N_ATOMS * 3);
    const int chunks = 128;

    // Replicated global histograms to spread end-of-block atomic contention,
    // gated on available workspace.
    int reps = 1;
    if (ws_size >= (size_t)(16 * MAX_B * sizeof(float))) reps = 16;
    else if (ws_size >= (size_t)(4 * MAX_B * sizeof(float))) reps = 4;

    hipLaunchKernelGGL(zero_hist_kernel, dim3(1), dim3(256), 0, stream,
                       hist, reps * MAX_B);
    hipLaunchKernelGGL(pair_kernel, dim3(F * chunks), dim3(256), 0, stream,
                       traj, cell, r_list, hist, B, chunks, reps);
    hipLaunchKernelGGL(finalize_kernel, dim3(1), dim3(MAX_B), 0, stream,
                       r_list, cell, hist, out, B, F, reps);
}

// Round 3
// 76.694 us; speedup vs baseline: 2.8053x; 1.3943x over previous
//
#include <hip/hip_runtime.h>
#include <math.h>

#define N_ATOMS 512
#define MAX_B 128
#define NBUCK 32
#define WIN 0.65f   // 6.5 sigma; exp(-50*0.65^2) ~ 7e-10, negligible vs 0.235 budget

__global__ void zero_kernel(float* p, int n) {
    int t = blockIdx.x * blockDim.x + threadIdx.x;
    if (t < n) p[t] = 0.0f;
}

// Grid: F * 64 blocks, 256 threads. Block = (frame, 4 bow-tie row-pairs) = 2048 pairs.
__global__ __launch_bounds__(256) void pair_kernel(
    const float* __restrict__ traj, const float* __restrict__ cell,
    const float* __restrict__ r_list, float* __restrict__ part,
    int B, int atomic_mode)
{
    __shared__ float qx[N_ATOMS], qy[N_ATOMS], qz[N_ATOMS];
    __shared__ float dsorted[2048];
    __shared__ int   cnt[NBUCK];
    __shared__ int   start[NBUCK + 1];
    __shared__ int   cursor[NBUCK];
    __shared__ float accbuf[256];

    const int frame = blockIdx.x >> 6;
    const int sub   = blockIdx.x & 63;
    const int tid   = threadIdx.x;

    const float* q = traj + (size_t)frame * (N_ATOMS * 3);
    for (int a = tid; a < N_ATOMS; a += 256) {
        qx[a] = q[3 * a + 0];
        qy[a] = q[3 * a + 1];
        qz[a] = q[3 * a + 2];
    }
    if (tid < NBUCK) cnt[tid] = 0;
    __syncthreads();

    const float L = cell[0];
    const float invL = 1.0f / L;
    const float cutoff_sq = 0.25f * L * L;
    const float inv_bw = (float)NBUCK / (0.5f * L);   // bucket = d * inv_bw in [0, NBUCK)

    // ---- phase 1a: distances + bucket counts (8 pairs per thread) ----
    float dval[8];
    int   dbuck[8];
    #pragma unroll
    for (int s = 0; s < 8; ++s) {
        const int qidx = s * 256 + tid;            // [0, 2048)
        const int rp   = sub * 4 + (qidx >> 9);    // row-pair [0, 256)
        const int qq   = qidx & 511;
        const int lenA = 511 - rp;                 // row rp: j in (rp, 511]
        const bool inA = qq < lenA;
        const int i = inA ? rp : (510 - rp);       // partner row 510-rp
        const int j = inA ? (rp + 1 + qq) : qq;    // row B: j == qq (exact)
        const bool vp = !(rp == 255 && !inA);      // rp==255 pairs with itself: half only

        float dx = qx[j] - qx[i];
        float dy = qy[j] - qy[i];
        float dz = qz[j] - qz[i];
        dx -= L * floorf(dx * invL + 0.5f);
        dy -= L * floorf(dy * invL + 0.5f);
        dz -= L * floorf(dz * invL + 0.5f);
        const float d2 = dx * dx + dy * dy + dz * dz;

        dbuck[s] = -1;
        dval[s]  = 0.0f;
        if (vp && d2 < cutoff_sq && d2 != 0.0f) {
            const float d = sqrtf(d2);
            int b = (int)(d * inv_bw);
            if (b > NBUCK - 1) b = NBUCK - 1;
            dval[s]  = d;
            dbuck[s] = b;
            atomicAdd(&cnt[b], 1);                 // native ds_add_u32
        }
    }
    __syncthreads();

    // ---- phase 1b: exclusive prefix scan of 32 bucket counts (one wave) ----
    if (tid < NBUCK) {
        const int v = cnt[tid];
        int incl = v;
        #pragma unroll
        for (int off = 1; off < NBUCK; off <<= 1) {
            const int n = __shfl_up(incl, off, 64);
            if (tid >= off) incl += n;
        }
        start[tid + 1] = incl;
        cursor[tid] = incl - v;
        if (tid == 0) start[0] = 0;
    }
    __syncthreads();

    // ---- phase 1c: scatter distances into bucket-sorted order ----
    #pragma unroll
    for (int s = 0; s < 8; ++s) {
        if (dbuck[s] >= 0) {
            const int pos = atomicAdd(&cursor[dbuck[s]], 1);
            dsorted[pos] = dval[s];
        }
    }
    __syncthreads();

    // ---- phase 2: bin-centric accumulation over windowed bucket range ----
    const int k = tid & 127;
    const int g = tid >> 7;
    float acc = 0.0f;
    if (k < B) {
        const float rk = r_list[k];
        const float c1 = -50.0f;
        const float c2 = 100.0f * rk;
        const float c3 = -50.0f * rk * rk;
        int blo = (int)(fmaxf((rk - WIN) * inv_bw, 0.0f));
        int bhi = (int)((rk + WIN) * inv_bw);
        if (bhi > NBUCK - 1) bhi = NBUCK - 1;
        const int lo = start[blo];
        const int hi = start[bhi + 1];
        for (int idx = lo + g; idx < hi; idx += 2) {
            const float d = dsorted[idx];
            acc += __expf(fmaf(d, fmaf(c1, d, c2), c3));
        }
    }
    accbuf[tid] = acc;
    __syncthreads();

    if (tid < 128) {
        const float v = accbuf[tid] + accbuf[tid + 128];
        if (atomic_mode) atomicAdd(&part[(blockIdx.x & 15) * MAX_B + tid], v);
        else             part[(size_t)blockIdx.x * MAX_B + tid] = v;
    }
}

// Grid: 128 blocks; block k reduces bin k over nrows partial histograms.
__global__ __launch_bounds__(256) void finalize_kernel(
    const float* __restrict__ r_list, const float* __restrict__ cell,
    const float* __restrict__ part, float* __restrict__ out,
    int B, int F, int nrows)
{
    __shared__ float red[256];
    const int k = blockIdx.x;
    if (k >= B) return;

    float s = 0.0f;
    for (int t = threadIdx.x; t < nrows; t += 256) s += part[(size_t)t * MAX_B + k];
    red[threadIdx.x] = s;
    __syncthreads();
    for (int off = 128; off > 0; off >>= 1) {
        if (threadIdx.x < off) red[threadIdx.x] += red[threadIdx.x + off];
        __syncthreads();
    }
    if (threadIdx.x == 0) {
        const float r = r_list[k];
        out[k] = r;                                    // output 0: r_list
        const float det = cell[0] * cell[4] * cell[8];
        const float rp = r + 0.05f;
        const float rm = r - 0.05f;
        const float v = (4.0f * (float)M_PI / 3.0f) * (rp * rp * rp - rm * rm * rm);
        const float inv_sqrt2pi = 0.3989422804014327f;
        const float h = red[0] * inv_sqrt2pi / (float)F;
        const float gr = h / v * det / (float)(N_ATOMS - 1) / (float)N_ATOMS * 2.0f;
        out[B + k] = gr;                               // output 1: gr
    }
}

extern "C" void kernel_launch(void* const* d_in, const int* in_sizes, int n_in,
                              void* d_out, int out_size, void* d_ws, size_t ws_size,
                              hipStream_t stream) {
    const float* traj   = (const float*)d_in[0];
    const float* cell   = (const float*)d_in[1];
    const float* r_list = (const float*)d_in[2];
    float* out  = (float*)d_out;
    float* part = (float*)d_ws;

    const int B = in_sizes[2];
    const int F = in_sizes[0] / (N_ATOMS * 3);
    const int nblocks = F * 64;

    const bool partials_fit =
        ws_size >= (size_t)nblocks * MAX_B * sizeof(float);

    if (partials_fit) {
        // 2 dispatches: unique-slot partials (no init needed), then reduce.
        hipLaunchKernelGGL(pair_kernel, dim3(nblocks), dim3(256), 0, stream,
                           traj, cell, r_list, part, B, 0);
        hipLaunchKernelGGL(finalize_kernel, dim3(MAX_B), dim3(256), 0, stream,
                           r_list, cell, part, out, B, F, nblocks);
    } else {
        // Fallback: 16 replicated atomic histograms (8 KB), needs zeroing.
        hipLaunchKernelGGL(zero_kernel, dim3(8), dim3(256), 0, stream,
                           part, 16 * MAX_B);
        hipLaunchKernelGGL(pair_kernel, dim3(nblocks), dim3(256), 0, stream,
                           traj, cell, r_list, part, B, 1);
        hipLaunchKernelGGL(finalize_kernel, dim3(MAX_B), dim3(256), 0, stream,
                           r_list, cell, part, out, B, F, 16);
    }
}